// Round 4
// baseline (551.121 us; speedup 1.0000x reference)
//
#include <hip/hip_runtime.h>

// Problem: B=4, N=2048, C=768, H=12, D=64. I/O tensors are FLOAT32 (per the
// reference setup_inputs); internals run bf16 MFMA with f32 accumulate.
// R4 root-cause: rounds 1-3 read f32 inputs as bf16 -> mantissa bits decoded
// as exponent 0xFF -> NaN everywhere. The "bf16" in the harness error label is
// hard-coded f-string text, not a dtype.
// Pipeline: LN(f32->bf16) -> QKV GEMM (Q*0.125 [B,H,N,D], K [B,H,N,D], V^T [B,H,D,N])
//           -> flash attention -> out-proj GEMM (+f32 bias +f32 residual -> f32 out).

typedef __bf16 bf16x8 __attribute__((ext_vector_type(8)));
typedef float  f32x4  __attribute__((ext_vector_type(4)));

#define MFMA16(a,b,c) __builtin_amdgcn_mfma_f32_16x16x32_bf16((a),(b),(c),0,0,0)

__device__ inline f32x4 zero4() { f32x4 z = {0.f,0.f,0.f,0.f}; return z; }

// ---------------- LayerNorm: one block per row of 768; f32 in, bf16 out ----------------
__global__ __launch_bounds__(256) void ln_kernel(const float* __restrict__ x,
                                                 const float* __restrict__ g,
                                                 const float* __restrict__ bt,
                                                 __bf16* __restrict__ xn) {
  const int row = blockIdx.x;
  const int tid = threadIdx.x;
  const float* xr = x + (size_t)row * 768;
  float v[3]; float s = 0.f, ss = 0.f;
  #pragma unroll
  for (int i = 0; i < 3; ++i) { float f = xr[tid + 256*i]; v[i] = f; s += f; ss += f*f; }
  #pragma unroll
  for (int m = 32; m >= 1; m >>= 1) { s += __shfl_xor(s, m, 64); ss += __shfl_xor(ss, m, 64); }
  __shared__ float red[8];
  const int wave = tid >> 6;
  if ((tid & 63) == 0) { red[wave] = s; red[4 + wave] = ss; }
  __syncthreads();
  s  = red[0] + red[1] + red[2] + red[3];
  ss = red[4] + red[5] + red[6] + red[7];
  const float mu  = s * (1.f/768.f);
  const float var = ss * (1.f/768.f) - mu*mu;
  const float inv = rsqrtf(var + 1e-5f);
  __bf16* xo = xn + (size_t)row * 768;
  #pragma unroll
  for (int i = 0; i < 3; ++i) {
    const int c0 = tid + 256*i;
    xo[c0] = (__bf16)((v[i] - mu) * inv * g[c0] + bt[c0]);
  }
}

// ---------------- 32x32 tiled transpose + f32->bf16: in[R][C] f32 -> out[C][R] bf16 ----------------
__global__ __launch_bounds__(256) void transpose_kernel(const float* __restrict__ in,
                                                        __bf16* __restrict__ out,
                                                        int R, int C) {
  __shared__ float t[32][33];
  const int tx = threadIdx.x & 31, ty = threadIdx.x >> 5;
  const int c0 = blockIdx.x * 32, r0 = blockIdx.y * 32;
  #pragma unroll
  for (int p = 0; p < 4; ++p) t[ty + 8*p][tx] = in[(size_t)(r0 + ty + 8*p) * C + c0 + tx];
  __syncthreads();
  #pragma unroll
  for (int p = 0; p < 4; ++p) out[(size_t)(c0 + ty + 8*p) * R + r0 + tx] = (__bf16)t[tx][ty + 8*p];
}

// ---------------- GEMM mainloop: C[128x128] = A[M,K] @ BT[N,K]^T (bf16) ----------------
// LDS layout per 16x32 subtile (blk): 1KB contiguous, elem idx = blk*512 + k8*128 + r*8 + j.
// Register-staged: thread (wave,lane,s2) loads 16B of row (blk*16 + lane&15),
// k-offset (lane>>4)*8, stores at blk*512 + lane*8 — covers all 8*512 elems.
// Frag read for MFMA A[m=lane&15][k=quad*8+j]: idx = lane*8 + j, 16B sequential.
template<int KDIM>
__device__ inline void gemm_mainloop(const __bf16* __restrict__ A, const __bf16* __restrict__ BT,
                                     int bm, int bn, int wave, int lane,
                                     f32x4 acc[4][4], __bf16* Asm, __bf16* Bsm) {
  const int wm = wave >> 1, wn = wave & 1;
  const int lr = lane & 15, lk = lane >> 4;
  for (int k0 = 0; k0 < KDIM; k0 += 32) {
    #pragma unroll
    for (int s2 = 0; s2 < 2; ++s2) {
      const int blk = wave * 2 + s2;
      const bf16x8 av = *(const bf16x8*)(A  + (size_t)(bm + blk*16 + lr) * KDIM + k0 + lk*8);
      const bf16x8 bv = *(const bf16x8*)(BT + (size_t)(bn + blk*16 + lr) * KDIM + k0 + lk*8);
      *(bf16x8*)(Asm + blk*512 + lane*8) = av;
      *(bf16x8*)(Bsm + blk*512 + lane*8) = bv;
    }
    __syncthreads();
    bf16x8 a[4], b[4];
    #pragma unroll
    for (int mt = 0; mt < 4; ++mt) a[mt] = *(const bf16x8*)(Asm + (wm*4+mt)*512 + lane*8);
    #pragma unroll
    for (int nt = 0; nt < 4; ++nt) b[nt] = *(const bf16x8*)(Bsm + (wn*4+nt)*512 + lane*8);
    #pragma unroll
    for (int mt = 0; mt < 4; ++mt)
      #pragma unroll
      for (int nt = 0; nt < 4; ++nt)
        acc[mt][nt] = MFMA16(a[mt], b[nt], acc[mt][nt]);
    __syncthreads();
  }
}

// ---------------- QKV GEMM: xn[8192,768] @ wqkvT[2304,768]^T ----------------
__global__ __launch_bounds__(256) void gemm_qkv_kernel(const __bf16* __restrict__ A,
                                                       const __bf16* __restrict__ BT,
                                                       __bf16* __restrict__ q,
                                                       __bf16* __restrict__ k,
                                                       __bf16* __restrict__ vt) {
  __shared__ __align__(16) __bf16 Asm[8*512];
  __shared__ __align__(16) __bf16 Bsm[8*512];
  const int lane = threadIdx.x & 63, wave = threadIdx.x >> 6;
  const int bm = blockIdx.y * 128, bn = blockIdx.x * 128;
  f32x4 acc[4][4];
  #pragma unroll
  for (int i = 0; i < 4; ++i)
    #pragma unroll
    for (int j = 0; j < 4; ++j) acc[i][j] = zero4();
  gemm_mainloop<768>(A, BT, bm, bn, wave, lane, acc, Asm, Bsm);
  const int wm = wave >> 1, wn = wave & 1;
  const int quad = lane >> 4, c = lane & 15;
  #pragma unroll
  for (int mt = 0; mt < 4; ++mt)
    #pragma unroll
    for (int nt = 0; nt < 4; ++nt) {
      const int col = bn + wn*64 + nt*16 + c;           // 0..2303
      const int which = col / 768, within = col % 768;
      const int h = within >> 6, d = within & 63;
      #pragma unroll
      for (int r = 0; r < 4; ++r) {
        const int row = bm + wm*64 + mt*16 + quad*4 + r; // 0..8191
        const int b = row >> 11, n = row & 2047;
        const float v = acc[mt][nt][r];
        const size_t bh = (size_t)(b*12 + h);
        if (which == 0)      q[(bh*2048 + n)*64 + d] = (__bf16)(v * 0.125f); // fold 1/sqrt(64)
        else if (which == 1) k[(bh*2048 + n)*64 + d] = (__bf16)v;
        else                 vt[(bh*64 + d)*2048 + n] = (__bf16)v;           // V transposed
      }
    }
}

// ---------------- Out-proj GEMM: o[8192,768] @ woutT[768,768]^T + f32 bias + f32 residual ----------------
__global__ __launch_bounds__(256) void gemm_out_kernel(const __bf16* __restrict__ A,
                                                       const __bf16* __restrict__ BT,
                                                       const float* __restrict__ bias,
                                                       const float* __restrict__ resid,
                                                       float* __restrict__ out) {
  __shared__ __align__(16) __bf16 Asm[8*512];
  __shared__ __align__(16) __bf16 Bsm[8*512];
  const int lane = threadIdx.x & 63, wave = threadIdx.x >> 6;
  const int bm = blockIdx.y * 128, bn = blockIdx.x * 128;
  f32x4 acc[4][4];
  #pragma unroll
  for (int i = 0; i < 4; ++i)
    #pragma unroll
    for (int j = 0; j < 4; ++j) acc[i][j] = zero4();
  gemm_mainloop<768>(A, BT, bm, bn, wave, lane, acc, Asm, Bsm);
  const int wm = wave >> 1, wn = wave & 1;
  const int quad = lane >> 4, c = lane & 15;
  #pragma unroll
  for (int mt = 0; mt < 4; ++mt)
    #pragma unroll
    for (int nt = 0; nt < 4; ++nt) {
      const int col = bn + wn*64 + nt*16 + c;
      #pragma unroll
      for (int r = 0; r < 4; ++r) {
        const int row = bm + wm*64 + mt*16 + quad*4 + r;
        out[(size_t)row*768 + col] = acc[mt][nt][r] + bias[col] + resid[(size_t)row*768 + col];
      }
    }
}

// ---------------- Flash attention: 1 block = (b,h) x 64 q-rows; 4 waves x 16 rows ----------------
__global__ __launch_bounds__(256) void attn_kernel(const __bf16* __restrict__ q,
                                                   const __bf16* __restrict__ k,
                                                   const __bf16* __restrict__ vt,
                                                   __bf16* __restrict__ o) {
  const int bh = blockIdx.x >> 5;     // 0..47, consecutive blocks share (b,h) -> K/V L2 reuse
  const int qt = blockIdx.x & 31;
  const int lane = threadIdx.x & 63, wave = threadIdx.x >> 6;
  const int c = lane & 15, quad = lane >> 4;
  const int q0 = qt*64 + wave*16;

  const __bf16* qb = q  + ((size_t)bh*2048 + q0) * 64;
  const __bf16* kb = k  + (size_t)bh * 2048 * 64;
  const __bf16* vb = vt + (size_t)bh * 64 * 2048;

  // Q A-frags (rows c, d = quad*8+j [+32]) — Q pre-scaled by 1/8
  const bf16x8 aq0 = *(const bf16x8*)(qb + c*64 + quad*8);
  const bf16x8 aq1 = *(const bf16x8*)(qb + c*64 + 32 + quad*8);

  float m[4], l[4];
  f32x4 od[4];
  #pragma unroll
  for (int r = 0; r < 4; ++r) { m[r] = -1.0e30f; l[r] = 0.f; }
  #pragma unroll
  for (int dt = 0; dt < 4; ++dt) od[dt] = zero4();

  // per-wave P staging: C-layout -> A-layout round trip (16x64 bf16),
  // double-buffered + one __syncthreads per iter ordering write->read.
  __shared__ __align__(16) __bf16 plds[2][4][1024];

  for (int kt = 0; kt < 2048; kt += 64) {
    __bf16* myp = plds[(kt >> 6) & 1][wave];
    // S = (Q/8) K^T for 64 keys: 4 subtiles of 16 keys
    f32x4 s[4];
    #pragma unroll
    for (int t = 0; t < 4; ++t) {
      const __bf16* kp = kb + (size_t)(kt + t*16 + c) * 64 + quad*8;
      const bf16x8 b0 = *(const bf16x8*)(kp);
      const bf16x8 b1 = *(const bf16x8*)(kp + 32);
      f32x4 z = zero4();
      z = MFMA16(aq0, b0, z);
      z = MFMA16(aq1, b1, z);
      s[t] = z;
    }
    // online softmax; row r lives on the 16 lanes of this quad group
    float cm[4], alpha[4], cl[4];
    #pragma unroll
    for (int r = 0; r < 4; ++r) {
      float v0 = fmaxf(fmaxf(s[0][r], s[1][r]), fmaxf(s[2][r], s[3][r]));
      v0 = fmaxf(v0, __shfl_xor(v0, 1)); v0 = fmaxf(v0, __shfl_xor(v0, 2));
      v0 = fmaxf(v0, __shfl_xor(v0, 4)); v0 = fmaxf(v0, __shfl_xor(v0, 8));
      cm[r] = v0;
    }
    #pragma unroll
    for (int r = 0; r < 4; ++r) {
      const float nm = fmaxf(m[r], cm[r]);
      alpha[r] = __expf(m[r] - nm);
      m[r] = nm; cl[r] = 0.f;
    }
    #pragma unroll
    for (int t = 0; t < 4; ++t)
      #pragma unroll
      for (int r = 0; r < 4; ++r) {
        const float p = __expf(s[t][r] - m[r]);
        s[t][r] = p; cl[r] += p;
      }
    #pragma unroll
    for (int r = 0; r < 4; ++r) {
      float v0 = cl[r];
      v0 += __shfl_xor(v0, 1); v0 += __shfl_xor(v0, 2);
      v0 += __shfl_xor(v0, 4); v0 += __shfl_xor(v0, 8);
      l[r] = l[r] * alpha[r] + v0;
    }
    #pragma unroll
    for (int dt = 0; dt < 4; ++dt)
      #pragma unroll
      for (int r = 0; r < 4; ++r) od[dt][r] *= alpha[r];
    // P (C-layout) -> LDS in A-frag-contiguous layout: idx = ks*512 + k8*128 + row*8 + j
    #pragma unroll
    for (int t = 0; t < 4; ++t) {
      const int kk = t*16 + c;
      const int base = (kk >> 5)*512 + ((kk >> 3) & 3)*128 + (kk & 7);
      #pragma unroll
      for (int r = 0; r < 4; ++r)
        myp[base + (quad*4 + r)*8] = (__bf16)s[t][r];
    }
    __syncthreads();   // order P-writes before P-reads (all waves in lockstep)
    const bf16x8 ap0 = *(const bf16x8*)(myp + lane*8);        // k 0..31
    const bf16x8 ap1 = *(const bf16x8*)(myp + 512 + lane*8);  // k 32..63
    // O += P V ; V^T rows are d, contiguous keys -> 16B loads
    #pragma unroll
    for (int dt = 0; dt < 4; ++dt) {
      const __bf16* vp = vb + (size_t)(dt*16 + c) * 2048 + kt + quad*8;
      const bf16x8 bv0 = *(const bf16x8*)(vp);
      const bf16x8 bv1 = *(const bf16x8*)(vp + 32);
      od[dt] = MFMA16(ap0, bv0, od[dt]);
      od[dt] = MFMA16(ap1, bv1, od[dt]);
    }
  }
  const int b = bh / 12, h = bh % 12;
  float rl[4];
  #pragma unroll
  for (int r = 0; r < 4; ++r) rl[r] = 1.f / l[r];
  #pragma unroll
  for (int dt = 0; dt < 4; ++dt)
    #pragma unroll
    for (int r = 0; r < 4; ++r) {
      const int n = q0 + quad*4 + r;
      const int col = h*64 + dt*16 + c;
      o[((size_t)b*2048 + n)*768 + col] = (__bf16)(od[dt][r] * rl[r]);
    }
}

extern "C" void kernel_launch(void* const* d_in, const int* in_sizes, int n_in,
                              void* d_out, int out_size, void* d_ws, size_t ws_size,
                              hipStream_t stream) {
  const float* img   = (const float*)d_in[0];
  const float* gamma = (const float*)d_in[1];
  const float* beta  = (const float*)d_in[2];
  const float* wqkv  = (const float*)d_in[3];
  const float* wout  = (const float*)d_in[4];
  const float* bout  = (const float*)d_in[5];
  float* out = (float*)d_out;

  __bf16* ws = (__bf16*)d_ws;
  size_t off = 0;
  __bf16* xn    = ws + off; off += (size_t)8192*768;   // LN output (bf16)
  __bf16* wqkvT = ws + off; off += (size_t)2304*768;   // w_qkv^T (bf16)
  __bf16* woutT = ws + off; off += (size_t)768*768;    // w_out^T (bf16)
  __bf16* qs    = ws + off; off += (size_t)48*2048*64; // Q/8   [B,H,N,D]
  __bf16* ks    = ws + off; off += (size_t)48*2048*64; // K     [B,H,N,D]
  __bf16* vts   = ws + off; off += (size_t)48*64*2048; // V^T   [B,H,D,N]
  __bf16* os    = ws + off; off += (size_t)8192*768;   // attn out [B,N,C]

  ln_kernel<<<8192, 256, 0, stream>>>(img, gamma, beta, xn);
  transpose_kernel<<<dim3(72, 24), 256, 0, stream>>>(wqkv, wqkvT, 768, 2304);
  transpose_kernel<<<dim3(24, 24), 256, 0, stream>>>(wout, woutT, 768, 768);
  gemm_qkv_kernel<<<dim3(18, 64), 256, 0, stream>>>(xn, wqkvT, qs, ks, vts);
  attn_kernel<<<1536, 256, 0, stream>>>(qs, ks, vts, os);
  gemm_out_kernel<<<dim3(6, 64), 256, 0, stream>>>(os, woutT, bout, img, out);
}